// Round 2
// baseline (562.699 us; speedup 1.0000x reference)
//
#include <hip/hip_runtime.h>
#include <stdint.h>

// ---------------------------------------------------------------------------
// WeedLayer: pooled-patch transformer layer + segment-stat scatter. fp32 I/O.
// B=8, C=64, H=W=256, PD=32, STRIDE=16 -> n=15, L=225, P=16, E=512, HEADS=8,
// hd=64, fv=4096. Row matrix X = [patches(128); blocks(1800)] = 1928 rows.
// R2: m97-style 128x128 MFMA GEMM w/ global_load_lds(16B); split-K=4 GEMM1;
//     fused QKV GEMM; LDS-staged attention; fused gelu+Wc; merged f2bf.
// ---------------------------------------------------------------------------

typedef __attribute__((ext_vector_type(8))) short bf16x8;
typedef __attribute__((ext_vector_type(4))) float f32x4;

__device__ __forceinline__ unsigned short f2bf(float x) {
    union { float f; unsigned u; } v; v.f = x;
    unsigned r = v.u + 0x7FFFu + ((v.u >> 16) & 1u);   // RNE
    return (unsigned short)(r >> 16);
}
__device__ __forceinline__ float bf2f(unsigned short x) {
    union { unsigned u; float f; } v; v.u = ((unsigned)x) << 16; return v.f;
}

// async 16B global -> LDS (wave-uniform LDS base + lane*16)
__device__ __forceinline__ void g2l16(const unsigned short* g, unsigned short* l) {
    __builtin_amdgcn_global_load_lds(
        (const __attribute__((address_space(1))) unsigned int*)g,
        (__attribute__((address_space(3))) unsigned int*)l, 16, 0, 0);
}

// --- K1: global 4ch x 2x2 pool of features -> Gp bf16 (8,16,128,128) --------
__global__ __launch_bounds__(256) void k_pool_features(
    const float* __restrict__ f, unsigned short* __restrict__ gp)
{
    unsigned t = blockIdx.x * 256u + threadIdx.x;        // 2,097,152 total
    unsigned q = t & 127u, r = (t >> 7) & 127u, g = (t >> 14) & 15u, b = t >> 18;
    const float2* f2 = (const float2*)f;
    float s = 0.f;
    unsigned cb = b * 64u + g * 4u;
#pragma unroll
    for (int j = 0; j < 4; ++j) {
#pragma unroll
        for (int a = 0; a < 2; ++a) {
            unsigned idx = ((cb + j) * 256u + 2u * r + a) * 256u + 2u * q;
            float2 v = f2[idx >> 1];
            s += v.x + v.y;
        }
    }
    gp[t] = f2bf(s * 0.0625f);
}

// --- K2: pool patches -> X rows 0..127 (bf16, 4096 cols) --------------------
__global__ __launch_bounds__(256) void k_pool_patches(
    const float* __restrict__ p, unsigned short* __restrict__ Xb)
{
    unsigned t = blockIdx.x * 256u + threadIdx.x;        // 524,288 total
    unsigned i = t & 4095u, row = t >> 12;
    unsigned q = i & 15u, r = (i >> 4) & 15u, g = i >> 8;
    const float2* p2 = (const float2*)p;
    float s = 0.f;
    unsigned cb = row * 64u + g * 4u;
#pragma unroll
    for (int j = 0; j < 4; ++j) {
#pragma unroll
        for (int a = 0; a < 2; ++a) {
            unsigned idx = ((cb + j) * 32u + 2u * r + a) * 32u + 2u * q;
            float2 v = p2[idx >> 1];
            s += v.x + v.y;
        }
    }
    Xb[(size_t)row * 4096 + i] = f2bf(s * 0.0625f);
}

// --- K3: gather block crops from Gp -> X rows 128..1927 ---------------------
__global__ __launch_bounds__(256) void k_gather_blocks(
    const unsigned short* __restrict__ Gp, unsigned short* __restrict__ Xb)
{
    unsigned t = blockIdx.x * 256u + threadIdx.x;        // 921,600 8-elt groups
    unsigned grp = t & 511u, row_rel = t >> 9;
    unsigned k0 = grp * 8u;
    unsigned g = k0 >> 8, r = (k0 >> 4) & 15u, q0 = k0 & 15u;
    unsigned b = row_rel / 225u;
    unsigned ij = row_rel - b * 225u;
    unsigned i = ij / 15u, j = ij - i * 15u;
    size_t src = ((size_t)(b * 16u + g) * 128u + i * 8u + r) * 128u + j * 8u + q0;
    size_t dst = (size_t)(128u + row_rel) * 4096u + k0;
    *(uint4*)(Xb + dst) = *(const uint4*)(Gp + src);
}

// --- K4: all weight fp32->bf16 in one launch --------------------------------
__global__ __launch_bounds__(256) void k_f2bf_all(
    const float* __restrict__ Wr, const float* __restrict__ Wqkv,
    const float* __restrict__ Wo, const float* __restrict__ Wm,
    unsigned short* __restrict__ oWr, unsigned short* __restrict__ oWqkv,
    unsigned short* __restrict__ oWo, unsigned short* __restrict__ oWm)
{
    int t = blockIdx.x * 256 + threadIdx.x;              // 851,968 float4 groups
    const float* src; unsigned short* dst; int i;
    if (t < 524288)      { src = Wr;   dst = oWr;   i = t; }
    else if (t < 720896) { src = Wqkv; dst = oWqkv; i = t - 524288; }
    else if (t < 786432) { src = Wo;   dst = oWo;   i = t - 720896; }
    else                 { src = Wm;   dst = oWm;   i = t - 786432; }
    float4 v = ((const float4*)src)[i];
    ushort4 o;
    o.x = f2bf(v.x); o.y = f2bf(v.y); o.z = f2bf(v.z); o.w = f2bf(v.w);
    ((ushort4*)dst)[i] = o;
}

// --- K5: 128x128-tile bf16 NT GEMM (m97 structure), optional split-K --------
// grid (N/128, ceil(M/128), splits); block 256. C partial s at C + s*M*N.
// A[M x K] (rows clamped to M-1), B[N x K], bias nullable (fp32 out + bias).
__global__ __launch_bounds__(256) void k_gemm128(
    const unsigned short* __restrict__ A, const unsigned short* __restrict__ Bw,
    const float* __restrict__ bias, float* __restrict__ C,
    int M, int N, int K, int klen)
{
    __shared__ __align__(16) unsigned short As[128 * 32];
    __shared__ __align__(16) unsigned short Bs[128 * 32];
    const int tid = threadIdx.x, w = tid >> 6, lane = tid & 63;
    const int nt = blockIdx.x, mt = blockIdx.y, ks = blockIdx.z;
    const int kbase = ks * klen;
    const int l15 = lane & 15, kq = (lane >> 4) * 8;
    const int wm = (w >> 1) * 64, wn = (w & 1) * 64;

    // staging geometry: wave w, call c stages rows [w*32+c*16, +16)
    const int srow0 = w * 32, lrow = lane >> 2, lcol = (lane & 3) * 8;

    f32x4 acc[4][4];
#pragma unroll
    for (int i = 0; i < 4; ++i)
#pragma unroll
        for (int j = 0; j < 4; ++j) acc[i][j] = (f32x4){0.f, 0.f, 0.f, 0.f};

    int arow0 = mt * 128, brow0 = nt * 128;
    for (int k0 = 0; k0 < klen; k0 += 32) {
        int kk = kbase + k0;
#pragma unroll
        for (int c = 0; c < 2; ++c) {
            int r = srow0 + c * 16 + lrow;
            int ga = arow0 + r; if (ga > M - 1) ga = M - 1;
            g2l16(A + (size_t)ga * K + kk + lcol, &As[(srow0 + c * 16) * 32]);
            g2l16(Bw + (size_t)(brow0 + r) * K + kk + lcol, &Bs[(srow0 + c * 16) * 32]);
        }
        __syncthreads();
        bf16x8 af[4], bf[4];
#pragma unroll
        for (int i = 0; i < 4; ++i) {
            af[i] = *(const bf16x8*)&As[(wm + 16 * i + l15) * 32 + kq];
            bf[i] = *(const bf16x8*)&Bs[(wn + 16 * i + l15) * 32 + kq];
        }
#pragma unroll
        for (int i = 0; i < 4; ++i)
#pragma unroll
            for (int j = 0; j < 4; ++j)
                acc[i][j] = __builtin_amdgcn_mfma_f32_16x16x32_bf16(af[i], bf[j], acc[i][j], 0, 0, 0);
        __syncthreads();
    }
    float* Cp = C + (size_t)ks * M * N;
#pragma unroll
    for (int i = 0; i < 4; ++i) {
        int rowb = mt * 128 + wm + i * 16 + (lane >> 4) * 4;
#pragma unroll
        for (int j = 0; j < 4; ++j) {
            int col = nt * 128 + wn + j * 16 + l15;
            float bv = bias ? bias[col] : 0.f;
#pragma unroll
            for (int r = 0; r < 4; ++r) {
                int row = rowb + r;
                if (row < M) Cp[(size_t)row * N + col] = acc[i][j][r] + bv;
            }
        }
    }
}

// --- K6: small 64x64 NT GEMM for the 128-row layers -------------------------
__global__ __launch_bounds__(256) void k_gemm_nt(
    const unsigned short* __restrict__ A, const unsigned short* __restrict__ Bw,
    const float* __restrict__ bias, float* __restrict__ C,
    int M, int N, int K)
{
    __shared__ __align__(16) unsigned short As[64 * 32];
    __shared__ __align__(16) unsigned short Bs[64 * 32];
    const int tid = threadIdx.x;
    const int bm = blockIdx.y, bn = blockIdx.x;
    const int wave = tid >> 6, lane = tid & 63;
    const int wm = (wave >> 1) * 32, wn = (wave & 1) * 32;
    const int l15 = lane & 15, kq = (lane >> 4) * 8;
    const int srow = tid >> 2, scol = (tid & 3) * 8;
    const unsigned short* Ap = A + (size_t)(bm * 64 + srow) * K + scol;
    const unsigned short* Bp = Bw + (size_t)(bn * 64 + srow) * K + scol;

    f32x4 acc[2][2];
#pragma unroll
    for (int i = 0; i < 2; ++i)
#pragma unroll
        for (int j = 0; j < 2; ++j) acc[i][j] = (f32x4){0.f, 0.f, 0.f, 0.f};

    for (int k0 = 0; k0 < K; k0 += 32) {
        *(uint4*)&As[srow * 32 + scol] = *(const uint4*)(Ap + k0);
        *(uint4*)&Bs[srow * 32 + scol] = *(const uint4*)(Bp + k0);
        __syncthreads();
        bf16x8 a0 = *(const bf16x8*)&As[(wm + l15) * 32 + kq];
        bf16x8 a1 = *(const bf16x8*)&As[(wm + 16 + l15) * 32 + kq];
        bf16x8 b0 = *(const bf16x8*)&Bs[(wn + l15) * 32 + kq];
        bf16x8 b1 = *(const bf16x8*)&Bs[(wn + 16 + l15) * 32 + kq];
        acc[0][0] = __builtin_amdgcn_mfma_f32_16x16x32_bf16(a0, b0, acc[0][0], 0, 0, 0);
        acc[0][1] = __builtin_amdgcn_mfma_f32_16x16x32_bf16(a0, b1, acc[0][1], 0, 0, 0);
        acc[1][0] = __builtin_amdgcn_mfma_f32_16x16x32_bf16(a1, b0, acc[1][0], 0, 0, 0);
        acc[1][1] = __builtin_amdgcn_mfma_f32_16x16x32_bf16(a1, b1, acc[1][1], 0, 0, 0);
        __syncthreads();
    }
#pragma unroll
    for (int it = 0; it < 2; ++it) {
        int rowb = bm * 64 + wm + it * 16 + (lane >> 4) * 4;
#pragma unroll
        for (int iu = 0; iu < 2; ++iu) {
            int col = bn * 64 + wn + iu * 16 + l15;
            float bv = bias[col];
#pragma unroll
            for (int r = 0; r < 4; ++r) {
                int row = rowb + r;
                if (row < M) C[(size_t)row * N + col] = acc[it][iu][r] + bv;
            }
        }
    }
}

// --- K7: 4-partial reduce + bias + LayerNorm (wave/row) ---------------------
__global__ __launch_bounds__(256) void k_lnred(
    const float* __restrict__ Yp, const float* __restrict__ br,
    const float* __restrict__ gg, const float* __restrict__ bb,
    float* __restrict__ outF, unsigned short* __restrict__ outB, int rows)
{
    int wave = threadIdx.x >> 6, lane = threadIdx.x & 63;
    int row = blockIdx.x * 4 + wave;
    if (row >= rows) return;
    size_t base = (size_t)row * 512 + lane * 8;
    float v[8];
    { const float* bp = br + lane * 8;
      float4 a = *(const float4*)bp, b = *(const float4*)(bp + 4);
      v[0]=a.x; v[1]=a.y; v[2]=a.z; v[3]=a.w; v[4]=b.x; v[5]=b.y; v[6]=b.z; v[7]=b.w; }
#pragma unroll
    for (int s = 0; s < 4; ++s) {
        const float* xp = Yp + (size_t)s * rows * 512 + base;
        float4 a = *(const float4*)xp, b = *(const float4*)(xp + 4);
        v[0]+=a.x; v[1]+=a.y; v[2]+=a.z; v[3]+=a.w; v[4]+=b.x; v[5]+=b.y; v[6]+=b.z; v[7]+=b.w;
    }
    float s = 0.f;
#pragma unroll
    for (int i = 0; i < 8; ++i) s += v[i];
#pragma unroll
    for (int m = 32; m; m >>= 1) s += __shfl_xor(s, m, 64);
    float mu = s * (1.f / 512.f);
    float sq = 0.f;
#pragma unroll
    for (int i = 0; i < 8; ++i) { float d = v[i] - mu; sq += d * d; }
#pragma unroll
    for (int m = 32; m; m >>= 1) sq += __shfl_xor(sq, m, 64);
    float rstd = rsqrtf(sq * (1.f / 512.f) + 1e-5f);
    const float* gp = gg + lane * 8;
    const float* bp2 = bb + lane * 8;
    float4 g0 = *(const float4*)gp, g1 = *(const float4*)(gp + 4);
    float4 b0 = *(const float4*)bp2, b1 = *(const float4*)(bp2 + 4);
    float ga[8] = {g0.x,g0.y,g0.z,g0.w,g1.x,g1.y,g1.z,g1.w};
    float ba[8] = {b0.x,b0.y,b0.z,b0.w,b1.x,b1.y,b1.z,b1.w};
    float o[8];
#pragma unroll
    for (int i = 0; i < 8; ++i) o[i] = (v[i] - mu) * rstd * ga[i] + ba[i];
    float* ofp = outF + base;
    float4 w0; w0.x=o[0]; w0.y=o[1]; w0.z=o[2]; w0.w=o[3];
    float4 w1; w1.x=o[4]; w1.y=o[5]; w1.z=o[6]; w1.w=o[7];
    *(float4*)ofp = w0; *(float4*)(ofp + 4) = w1;
    unsigned short* obp = outB + base;
    ushort4 u0, u1;
    u0.x=f2bf(o[0]); u0.y=f2bf(o[1]); u0.z=f2bf(o[2]); u0.w=f2bf(o[3]);
    u1.x=f2bf(o[4]); u1.y=f2bf(o[5]); u1.z=f2bf(o[6]); u1.w=f2bf(o[7]);
    ((ushort4*)obp)[0] = u0; ((ushort4*)obp)[1] = u1;
}

// --- K8: plain LayerNorm w/ residual (128 rows) -----------------------------
__global__ __launch_bounds__(256) void k_ln(
    const float* __restrict__ X, const float* __restrict__ R,
    const float* __restrict__ gg, const float* __restrict__ bb,
    float* __restrict__ outF, unsigned short* __restrict__ outB, int rows)
{
    int wave = threadIdx.x >> 6, lane = threadIdx.x & 63;
    int row = blockIdx.x * 4 + wave;
    if (row >= rows) return;
    size_t base = (size_t)row * 512 + lane * 8;
    const float* xp = X + base;
    float v[8];
    { float4 a = *(const float4*)xp, b = *(const float4*)(xp + 4);
      v[0]=a.x; v[1]=a.y; v[2]=a.z; v[3]=a.w; v[4]=b.x; v[5]=b.y; v[6]=b.z; v[7]=b.w; }
    { const float* rp = R + base;
      float4 a = *(const float4*)rp, b = *(const float4*)(rp + 4);
      v[0]+=a.x; v[1]+=a.y; v[2]+=a.z; v[3]+=a.w; v[4]+=b.x; v[5]+=b.y; v[6]+=b.z; v[7]+=b.w; }
    float s = 0.f;
#pragma unroll
    for (int i = 0; i < 8; ++i) s += v[i];
#pragma unroll
    for (int m = 32; m; m >>= 1) s += __shfl_xor(s, m, 64);
    float mu = s * (1.f / 512.f);
    float sq = 0.f;
#pragma unroll
    for (int i = 0; i < 8; ++i) { float d = v[i] - mu; sq += d * d; }
#pragma unroll
    for (int m = 32; m; m >>= 1) sq += __shfl_xor(sq, m, 64);
    float rstd = rsqrtf(sq * (1.f / 512.f) + 1e-5f);
    const float* gp = gg + lane * 8;
    const float* bp = bb + lane * 8;
    float4 g0 = *(const float4*)gp, g1 = *(const float4*)(gp + 4);
    float4 b0 = *(const float4*)bp, b1 = *(const float4*)(bp + 4);
    float ga[8] = {g0.x,g0.y,g0.z,g0.w,g1.x,g1.y,g1.z,g1.w};
    float ba[8] = {b0.x,b0.y,b0.z,b0.w,b1.x,b1.y,b1.z,b1.w};
    float o[8];
#pragma unroll
    for (int i = 0; i < 8; ++i) o[i] = (v[i] - mu) * rstd * ga[i] + ba[i];
    float* ofp = outF + base;
    float4 w0; w0.x=o[0]; w0.y=o[1]; w0.z=o[2]; w0.w=o[3];
    float4 w1; w1.x=o[4]; w1.y=o[5]; w1.z=o[6]; w1.w=o[7];
    *(float4*)ofp = w0; *(float4*)(ofp + 4) = w1;
    unsigned short* obp = outB + base;
    ushort4 u0, u1;
    u0.x=f2bf(o[0]); u0.y=f2bf(o[1]); u0.z=f2bf(o[2]); u0.w=f2bf(o[3]);
    u1.x=f2bf(o[4]); u1.y=f2bf(o[5]); u1.z=f2bf(o[6]); u1.w=f2bf(o[7]);
    ((ushort4*)obp)[0] = u0; ((ushort4*)obp)[1] = u1;
}

// --- K9: attention per (b,h); QKV fp32 [1928 x 1536]; V staged in LDS bf16 --
__global__ __launch_bounds__(256) void k_attn(
    const float* __restrict__ QKV, unsigned short* __restrict__ attn_bf)
{
    int b = blockIdx.x, h = blockIdx.y;
    __shared__ __align__(16) float qs[16 * 64];
    __shared__ unsigned short Vs[225 * 64];
    __shared__ float sc[16 * 225];
    int t = threadIdx.x;
    for (int i = t; i < 1024; i += 256) {
        int p = i >> 6, d = i & 63;
        qs[i] = QKV[(size_t)(b * 16 + p) * 1536 + h * 64 + d];
    }
    for (int i = t; i < 14400; i += 256) {
        int l = i >> 6, d = i & 63;
        Vs[i] = f2bf(QKV[(size_t)(128 + b * 225 + l) * 1536 + 1024 + h * 64 + d]);
    }
    __syncthreads();
    for (int i = t; i < 3600; i += 256) {
        int p = i / 225, l = i - p * 225;
        const float4* k4 = (const float4*)(QKV + (size_t)(128 + b * 225 + l) * 1536 + 512 + h * 64);
        const float4* q4 = (const float4*)&qs[p * 64];
        float s = 0.f;
#pragma unroll
        for (int d = 0; d < 16; ++d) {
            float4 kk = k4[d], qq = q4[d];
            s += kk.x * qq.x + kk.y * qq.y + kk.z * qq.z + kk.w * qq.w;
        }
        sc[p * 225 + l] = s * 0.125f;   // 1/sqrt(64)
    }
    __syncthreads();
    int lane = t & 63, wave = t >> 6;
    int p = wave * 4 + (lane >> 4), sub = lane & 15;
    float m = -1e30f;
    for (int l = sub; l < 225; l += 16) m = fmaxf(m, sc[p * 225 + l]);
#pragma unroll
    for (int off = 8; off; off >>= 1) m = fmaxf(m, __shfl_xor(m, off, 16));
    float s = 0.f;
    for (int l = sub; l < 225; l += 16) {
        float e = __expf(sc[p * 225 + l] - m);
        sc[p * 225 + l] = e; s += e;
    }
#pragma unroll
    for (int off = 8; off; off >>= 1) s += __shfl_xor(s, off, 16);
    float inv = 1.f / s;
    for (int l = sub; l < 225; l += 16) sc[p * 225 + l] *= inv;
    __syncthreads();
    for (int i = t; i < 1024; i += 256) {
        int p2 = i >> 6, d = i & 63;
        float o = 0.f;
        for (int l = 0; l < 225; ++l) o += sc[p2 * 225 + l] * bf2f(Vs[l * 64 + d]);
        attn_bf[(size_t)(b * 16 + p2) * 512 + h * 64 + d] = f2bf(o);
    }
}

// --- K10: outs[128,2] = (gelu(M1)+res) @ Wc^T + bc --------------------------
__global__ __launch_bounds__(256) void k_wc(
    const float* __restrict__ m1, const float* __restrict__ res,
    const float* __restrict__ Wc, const float* __restrict__ bc,
    float* __restrict__ outs)
{
    int t = threadIdx.x;                  // 128 rows x 2 cols
    int row = t >> 1, c = t & 1;
    const float* mp = m1 + (size_t)row * 512;
    const float* rp = res + (size_t)row * 512;
    const float* wp = Wc + (size_t)c * 512;
    float s = 0.f;
    for (int k = 0; k < 512; ++k) {
        float v = mp[k];
        float g = 0.5f * v * (1.f + erff(v * 0.70710678118654752f));
        s += (g + rp[k]) * wp[k];
    }
    outs[row * 2 + c] = s + bc[c];
}

// --- K11: zero helper --------------------------------------------------------
__global__ void k_zero(float* __restrict__ p, int n) {
    int t = blockIdx.x * blockDim.x + threadIdx.x;
    if (t < n) p[t] = 0.f;
}

// --- K12: segment histogram --------------------------------------------------
__global__ __launch_bounds__(256) void k_hist(
    const int* __restrict__ masks, const float* __restrict__ probs,
    float* __restrict__ sums, float* __restrict__ cnt)
{
    __shared__ float ls[68];
    int t = threadIdx.x;
    if (t < 68) ls[t] = 0.f;
    __syncthreads();
    int b = blockIdx.x >> 6, chunk = blockIdx.x & 63;
    int base = chunk * 1024;
    for (int it = 0; it < 4; ++it) {
        int px = base + it * 256 + t;
        int lab = masks[b * 65536 + px];
        atomicAdd(&ls[lab * 3 + 0], probs[(size_t)(b * 3 + 0) * 65536 + px]);
        atomicAdd(&ls[lab * 3 + 1], probs[(size_t)(b * 3 + 1) * 65536 + px]);
        atomicAdd(&ls[lab * 3 + 2], probs[(size_t)(b * 3 + 2) * 65536 + px]);
        atomicAdd(&ls[51 + lab], 1.f);
    }
    __syncthreads();
    if (t < 51)       atomicAdd(&sums[b * 51 + t], ls[t]);
    else if (t < 68)  atomicAdd(&cnt[b * 17 + t - 51], ls[t]);
}

// --- K13: newv table (8 x 17 x 3) --------------------------------------------
__global__ void k_newv(
    const float* __restrict__ seg, const float* __restrict__ outs,
    float* __restrict__ newv)
{
    int t = threadIdx.x;
    if (t >= 136) return;
    int lab = t % 17;
    const float* sums = seg;
    const float* cnt  = seg + 408;
    if (lab == 0) { newv[t*3+0] = 0.f; newv[t*3+1] = 0.f; newv[t*3+2] = 0.f; return; }
    int b = t / 17;
    float c  = fmaxf(cnt[t], 1.f);
    float m0 = sums[t*3+0] / c + 1e-6f;
    float m1 = sums[t*3+1] / c + 1e-6f;
    float m2 = sums[t*3+2] / c + 1e-6f;
    int p = lab - 1;
    float o0 = outs[(b*16+p)*2+0], o1 = outs[(b*16+p)*2+1];
    float new0 = m0 / (0.5f * (m1 + m2)) * (0.5f * (o0 + o1));
    newv[t*3+0] = new0; newv[t*3+1] = o0; newv[t*3+2] = o1;
}

// --- K14: final per-pixel gather ---------------------------------------------
__global__ __launch_bounds__(256) void k_out(
    const int* __restrict__ masks, const float* __restrict__ probs,
    const float* __restrict__ newv, float* __restrict__ out)
{
    int t = blockIdx.x * 256 + threadIdx.x;
    int b = t >> 16, hw = t & 65535;
    int lab = masks[t];
    if (lab > 0) {
        const float* nv = newv + (size_t)(b * 17 + lab) * 3;
        out[(size_t)(b*3+0)*65536 + hw] = nv[0];
        out[(size_t)(b*3+1)*65536 + hw] = nv[1];
        out[(size_t)(b*3+2)*65536 + hw] = nv[2];
    } else {
        out[(size_t)(b*3+0)*65536 + hw] = probs[(size_t)(b*3+0)*65536 + hw];
        out[(size_t)(b*3+1)*65536 + hw] = probs[(size_t)(b*3+1)*65536 + hw];
        out[(size_t)(b*3+2)*65536 + hw] = probs[(size_t)(b*3+2)*65536 + hw];
    }
}

// ---------------------------------------------------------------------------
extern "C" void kernel_launch(void* const* d_in, const int* in_sizes, int n_in,
                              void* d_out, int out_size, void* d_ws, size_t ws_size,
                              hipStream_t stream)
{
    const float* features = (const float*)d_in[0];
    const float* probs    = (const float*)d_in[1];
    const float* patches  = (const float*)d_in[2];
    const int*   masks    = (const int*)d_in[3];
    const float* ln_g     = (const float*)d_in[4];
    const float* ln_b     = (const float*)d_in[5];
    const float* Wr       = (const float*)d_in[6];
    const float* br       = (const float*)d_in[7];
    const float* Wqkv     = (const float*)d_in[8];
    const float* bqkv     = (const float*)d_in[9];
    const float* Wo       = (const float*)d_in[10];
    const float* bo       = (const float*)d_in[11];
    const float* Wm       = (const float*)d_in[12];
    const float* bm       = (const float*)d_in[13];
    const float* Wc       = (const float*)d_in[14];
    const float* bc       = (const float*)d_in[15];
    float* out = (float*)d_out;

    char* w = (char*)d_ws;
    size_t off = 0;
    auto alloc = [&](size_t bytes) -> char* {
        char* p = w + off;
        off += (bytes + 255) & ~(size_t)255;
        return p;
    };
    unsigned short* Gp     = (unsigned short*)alloc((size_t)2097152 * 2);
    unsigned short* Xb     = (unsigned short*)alloc((size_t)1928 * 4096 * 2);
    unsigned short* Wr_b   = (unsigned short*)alloc((size_t)2097152 * 2);
    unsigned short* Wqkv_b = (unsigned short*)alloc((size_t)786432 * 2);
    unsigned short* Wo_b   = (unsigned short*)alloc((size_t)262144 * 2);
    unsigned short* Wm_b   = (unsigned short*)alloc((size_t)262144 * 2);
    float* Yp   = (float*)alloc((size_t)4 * 1928 * 512 * 4);   // split-K partials
    float* LNf  = (float*)alloc((size_t)1928 * 512 * 4);
    unsigned short* LNb = (unsigned short*)alloc((size_t)1928 * 512 * 2);
    float* QKV  = (float*)alloc((size_t)1928 * 1536 * 4);
    unsigned short* attnb = (unsigned short*)alloc((size_t)65536 * 2);
    float* Zo   = (float*)alloc((size_t)65536 * 4);
    float* resf = (float*)alloc((size_t)65536 * 4);
    unsigned short* resb = (unsigned short*)alloc((size_t)65536 * 2);
    float* M1   = (float*)alloc((size_t)65536 * 4);
    float* outsB = (float*)alloc((size_t)256 * 4);
    float* seg   = (float*)alloc((size_t)544 * 4);
    float* newv  = (float*)alloc((size_t)408 * 4);

    k_zero<<<3, 256, 0, stream>>>(seg, 544);

    k_pool_features<<<8192, 256, 0, stream>>>(features, Gp);
    k_pool_patches<<<2048, 256, 0, stream>>>(patches, Xb);
    k_gather_blocks<<<3600, 256, 0, stream>>>(Gp, Xb);
    k_f2bf_all<<<3328, 256, 0, stream>>>(Wr, Wqkv, Wo, Wm, Wr_b, Wqkv_b, Wo_b, Wm_b);

    // GEMM1 split-K=4: Yp[s] = X @ Wr^T (1928 x 4096/4 x 512), 256 blocks
    k_gemm128<<<dim3(4, 16, 4), 256, 0, stream>>>(Xb, Wr_b, nullptr, Yp, 1928, 512, 4096, 1024);
    // reduce + br + LN1
    k_lnred<<<482, 256, 0, stream>>>(Yp, br, ln_g, ln_b, LNf, LNb, 1928);

    // fused QKV: [1928 x 1536] = LNb @ Wqkv^T + bqkv (192 blocks)
    k_gemm128<<<dim3(12, 16, 1), 256, 0, stream>>>(LNb, Wqkv_b, bqkv, QKV, 1928, 1536, 512, 512);

    k_attn<<<dim3(8, 8), 256, 0, stream>>>(QKV, attnb);

    k_gemm_nt<<<dim3(8, 2), 256, 0, stream>>>(attnb, Wo_b, bo, Zo, 128, 512, 512);
    k_ln<<<32, 256, 0, stream>>>(Zo, LNf, ln_g, ln_b, resf, resb, 128);

    k_gemm_nt<<<dim3(8, 2), 256, 0, stream>>>(resb, Wm_b, bm, M1, 128, 512, 512);
    k_wc<<<1, 256, 0, stream>>>(M1, resf, Wc, bc, outsB);

    k_hist<<<512, 256, 0, stream>>>(masks, probs, seg, seg + 408);
    k_newv<<<1, 256, 0, stream>>>(seg, outsB, newv);
    k_out<<<2048, 256, 0, stream>>>(masks, probs, newv, out);
}

// Round 3
// 406.547 us; speedup vs baseline: 1.3841x; 1.3841x over previous
//
#include <hip/hip_runtime.h>
#include <stdint.h>

// ---------------------------------------------------------------------------
// WeedLayer: pooled-patch transformer layer + segment-stat scatter. fp32 I/O.
// B=8, C=64, H=W=256, PD=32, STRIDE=16 -> n=15, L=225, P=16, E=512, HEADS=8,
// hd=64, fv=4096. Row matrix X = [patches(128); blocks(1800)] = 1928 rows.
// R3: fix k_wc regression (was 164us on 1 block) -> wave-per-row, 32 blocks.
// ---------------------------------------------------------------------------

typedef __attribute__((ext_vector_type(8))) short bf16x8;
typedef __attribute__((ext_vector_type(4))) float f32x4;

__device__ __forceinline__ unsigned short f2bf(float x) {
    union { float f; unsigned u; } v; v.f = x;
    unsigned r = v.u + 0x7FFFu + ((v.u >> 16) & 1u);   // RNE
    return (unsigned short)(r >> 16);
}
__device__ __forceinline__ float bf2f(unsigned short x) {
    union { unsigned u; float f; } v; v.u = ((unsigned)x) << 16; return v.f;
}

// async 16B global -> LDS (wave-uniform LDS base + lane*16)
__device__ __forceinline__ void g2l16(const unsigned short* g, unsigned short* l) {
    __builtin_amdgcn_global_load_lds(
        (const __attribute__((address_space(1))) unsigned int*)g,
        (__attribute__((address_space(3))) unsigned int*)l, 16, 0, 0);
}

// --- K1: global 4ch x 2x2 pool of features -> Gp bf16 (8,16,128,128) --------
__global__ __launch_bounds__(256) void k_pool_features(
    const float* __restrict__ f, unsigned short* __restrict__ gp)
{
    unsigned t = blockIdx.x * 256u + threadIdx.x;        // 2,097,152 total
    unsigned q = t & 127u, r = (t >> 7) & 127u, g = (t >> 14) & 15u, b = t >> 18;
    const float2* f2 = (const float2*)f;
    float s = 0.f;
    unsigned cb = b * 64u + g * 4u;
#pragma unroll
    for (int j = 0; j < 4; ++j) {
#pragma unroll
        for (int a = 0; a < 2; ++a) {
            unsigned idx = ((cb + j) * 256u + 2u * r + a) * 256u + 2u * q;
            float2 v = f2[idx >> 1];
            s += v.x + v.y;
        }
    }
    gp[t] = f2bf(s * 0.0625f);
}

// --- K2: pool patches -> X rows 0..127 (bf16, 4096 cols) --------------------
__global__ __launch_bounds__(256) void k_pool_patches(
    const float* __restrict__ p, unsigned short* __restrict__ Xb)
{
    unsigned t = blockIdx.x * 256u + threadIdx.x;        // 524,288 total
    unsigned i = t & 4095u, row = t >> 12;
    unsigned q = i & 15u, r = (i >> 4) & 15u, g = i >> 8;
    const float2* p2 = (const float2*)p;
    float s = 0.f;
    unsigned cb = row * 64u + g * 4u;
#pragma unroll
    for (int j = 0; j < 4; ++j) {
#pragma unroll
        for (int a = 0; a < 2; ++a) {
            unsigned idx = ((cb + j) * 32u + 2u * r + a) * 32u + 2u * q;
            float2 v = p2[idx >> 1];
            s += v.x + v.y;
        }
    }
    Xb[(size_t)row * 4096 + i] = f2bf(s * 0.0625f);
}

// --- K3: gather block crops from Gp -> X rows 128..1927 ---------------------
__global__ __launch_bounds__(256) void k_gather_blocks(
    const unsigned short* __restrict__ Gp, unsigned short* __restrict__ Xb)
{
    unsigned t = blockIdx.x * 256u + threadIdx.x;        // 921,600 8-elt groups
    unsigned grp = t & 511u, row_rel = t >> 9;
    unsigned k0 = grp * 8u;
    unsigned g = k0 >> 8, r = (k0 >> 4) & 15u, q0 = k0 & 15u;
    unsigned b = row_rel / 225u;
    unsigned ij = row_rel - b * 225u;
    unsigned i = ij / 15u, j = ij - i * 15u;
    size_t src = ((size_t)(b * 16u + g) * 128u + i * 8u + r) * 128u + j * 8u + q0;
    size_t dst = (size_t)(128u + row_rel) * 4096u + k0;
    *(uint4*)(Xb + dst) = *(const uint4*)(Gp + src);
}

// --- K4: all weight fp32->bf16 in one launch --------------------------------
__global__ __launch_bounds__(256) void k_f2bf_all(
    const float* __restrict__ Wr, const float* __restrict__ Wqkv,
    const float* __restrict__ Wo, const float* __restrict__ Wm,
    unsigned short* __restrict__ oWr, unsigned short* __restrict__ oWqkv,
    unsigned short* __restrict__ oWo, unsigned short* __restrict__ oWm)
{
    int t = blockIdx.x * 256 + threadIdx.x;              // 851,968 float4 groups
    const float* src; unsigned short* dst; int i;
    if (t < 524288)      { src = Wr;   dst = oWr;   i = t; }
    else if (t < 720896) { src = Wqkv; dst = oWqkv; i = t - 524288; }
    else if (t < 786432) { src = Wo;   dst = oWo;   i = t - 720896; }
    else                 { src = Wm;   dst = oWm;   i = t - 786432; }
    float4 v = ((const float4*)src)[i];
    ushort4 o;
    o.x = f2bf(v.x); o.y = f2bf(v.y); o.z = f2bf(v.z); o.w = f2bf(v.w);
    ((ushort4*)dst)[i] = o;
}

// --- K5: 128x128-tile bf16 NT GEMM (m97 structure), optional split-K --------
__global__ __launch_bounds__(256) void k_gemm128(
    const unsigned short* __restrict__ A, const unsigned short* __restrict__ Bw,
    const float* __restrict__ bias, float* __restrict__ C,
    int M, int N, int K, int klen)
{
    __shared__ __align__(16) unsigned short As[128 * 32];
    __shared__ __align__(16) unsigned short Bs[128 * 32];
    const int tid = threadIdx.x, w = tid >> 6, lane = tid & 63;
    const int nt = blockIdx.x, mt = blockIdx.y, ks = blockIdx.z;
    const int kbase = ks * klen;
    const int l15 = lane & 15, kq = (lane >> 4) * 8;
    const int wm = (w >> 1) * 64, wn = (w & 1) * 64;
    const int srow0 = w * 32, lrow = lane >> 2, lcol = (lane & 3) * 8;

    f32x4 acc[4][4];
#pragma unroll
    for (int i = 0; i < 4; ++i)
#pragma unroll
        for (int j = 0; j < 4; ++j) acc[i][j] = (f32x4){0.f, 0.f, 0.f, 0.f};

    int arow0 = mt * 128, brow0 = nt * 128;
    for (int k0 = 0; k0 < klen; k0 += 32) {
        int kk = kbase + k0;
#pragma unroll
        for (int c = 0; c < 2; ++c) {
            int r = srow0 + c * 16 + lrow;
            int ga = arow0 + r; if (ga > M - 1) ga = M - 1;
            g2l16(A + (size_t)ga * K + kk + lcol, &As[(srow0 + c * 16) * 32]);
            g2l16(Bw + (size_t)(brow0 + r) * K + kk + lcol, &Bs[(srow0 + c * 16) * 32]);
        }
        __syncthreads();
        bf16x8 af[4], bf[4];
#pragma unroll
        for (int i = 0; i < 4; ++i) {
            af[i] = *(const bf16x8*)&As[(wm + 16 * i + l15) * 32 + kq];
            bf[i] = *(const bf16x8*)&Bs[(wn + 16 * i + l15) * 32 + kq];
        }
#pragma unroll
        for (int i = 0; i < 4; ++i)
#pragma unroll
            for (int j = 0; j < 4; ++j)
                acc[i][j] = __builtin_amdgcn_mfma_f32_16x16x32_bf16(af[i], bf[j], acc[i][j], 0, 0, 0);
        __syncthreads();
    }
    float* Cp = C + (size_t)ks * M * N;
#pragma unroll
    for (int i = 0; i < 4; ++i) {
        int rowb = mt * 128 + wm + i * 16 + (lane >> 4) * 4;
#pragma unroll
        for (int j = 0; j < 4; ++j) {
            int col = nt * 128 + wn + j * 16 + l15;
            float bv = bias ? bias[col] : 0.f;
#pragma unroll
            for (int r = 0; r < 4; ++r) {
                int row = rowb + r;
                if (row < M) Cp[(size_t)row * N + col] = acc[i][j][r] + bv;
            }
        }
    }
}

// --- K6: small 64x64 NT GEMM for the 128-row layers -------------------------
__global__ __launch_bounds__(256) void k_gemm_nt(
    const unsigned short* __restrict__ A, const unsigned short* __restrict__ Bw,
    const float* __restrict__ bias, float* __restrict__ C,
    int M, int N, int K)
{
    __shared__ __align__(16) unsigned short As[64 * 32];
    __shared__ __align__(16) unsigned short Bs[64 * 32];
    const int tid = threadIdx.x;
    const int bm = blockIdx.y, bn = blockIdx.x;
    const int wave = tid >> 6, lane = tid & 63;
    const int wm = (wave >> 1) * 32, wn = (wave & 1) * 32;
    const int l15 = lane & 15, kq = (lane >> 4) * 8;
    const int srow = tid >> 2, scol = (tid & 3) * 8;
    const unsigned short* Ap = A + (size_t)(bm * 64 + srow) * K + scol;
    const unsigned short* Bp = Bw + (size_t)(bn * 64 + srow) * K + scol;

    f32x4 acc[2][2];
#pragma unroll
    for (int i = 0; i < 2; ++i)
#pragma unroll
        for (int j = 0; j < 2; ++j) acc[i][j] = (f32x4){0.f, 0.f, 0.f, 0.f};

    for (int k0 = 0; k0 < K; k0 += 32) {
        *(uint4*)&As[srow * 32 + scol] = *(const uint4*)(Ap + k0);
        *(uint4*)&Bs[srow * 32 + scol] = *(const uint4*)(Bp + k0);
        __syncthreads();
        bf16x8 a0 = *(const bf16x8*)&As[(wm + l15) * 32 + kq];
        bf16x8 a1 = *(const bf16x8*)&As[(wm + 16 + l15) * 32 + kq];
        bf16x8 b0 = *(const bf16x8*)&Bs[(wn + l15) * 32 + kq];
        bf16x8 b1 = *(const bf16x8*)&Bs[(wn + 16 + l15) * 32 + kq];
        acc[0][0] = __builtin_amdgcn_mfma_f32_16x16x32_bf16(a0, b0, acc[0][0], 0, 0, 0);
        acc[0][1] = __builtin_amdgcn_mfma_f32_16x16x32_bf16(a0, b1, acc[0][1], 0, 0, 0);
        acc[1][0] = __builtin_amdgcn_mfma_f32_16x16x32_bf16(a1, b0, acc[1][0], 0, 0, 0);
        acc[1][1] = __builtin_amdgcn_mfma_f32_16x16x32_bf16(a1, b1, acc[1][1], 0, 0, 0);
        __syncthreads();
    }
#pragma unroll
    for (int it = 0; it < 2; ++it) {
        int rowb = bm * 64 + wm + it * 16 + (lane >> 4) * 4;
#pragma unroll
        for (int iu = 0; iu < 2; ++iu) {
            int col = bn * 64 + wn + iu * 16 + l15;
            float bv = bias[col];
#pragma unroll
            for (int r = 0; r < 4; ++r) {
                int row = rowb + r;
                if (row < M) C[(size_t)row * N + col] = acc[it][iu][r] + bv;
            }
        }
    }
}

// --- K7: 4-partial reduce + bias + LayerNorm (wave/row) ---------------------
__global__ __launch_bounds__(256) void k_lnred(
    const float* __restrict__ Yp, const float* __restrict__ br,
    const float* __restrict__ gg, const float* __restrict__ bb,
    float* __restrict__ outF, unsigned short* __restrict__ outB, int rows)
{
    int wave = threadIdx.x >> 6, lane = threadIdx.x & 63;
    int row = blockIdx.x * 4 + wave;
    if (row >= rows) return;
    size_t base = (size_t)row * 512 + lane * 8;
    float v[8];
    { const float* bp = br + lane * 8;
      float4 a = *(const float4*)bp, b = *(const float4*)(bp + 4);
      v[0]=a.x; v[1]=a.y; v[2]=a.z; v[3]=a.w; v[4]=b.x; v[5]=b.y; v[6]=b.z; v[7]=b.w; }
#pragma unroll
    for (int s = 0; s < 4; ++s) {
        const float* xp = Yp + (size_t)s * rows * 512 + base;
        float4 a = *(const float4*)xp, b = *(const float4*)(xp + 4);
        v[0]+=a.x; v[1]+=a.y; v[2]+=a.z; v[3]+=a.w; v[4]+=b.x; v[5]+=b.y; v[6]+=b.z; v[7]+=b.w;
    }
    float s = 0.f;
#pragma unroll
    for (int i = 0; i < 8; ++i) s += v[i];
#pragma unroll
    for (int m = 32; m; m >>= 1) s += __shfl_xor(s, m, 64);
    float mu = s * (1.f / 512.f);
    float sq = 0.f;
#pragma unroll
    for (int i = 0; i < 8; ++i) { float d = v[i] - mu; sq += d * d; }
#pragma unroll
    for (int m = 32; m; m >>= 1) sq += __shfl_xor(sq, m, 64);
    float rstd = rsqrtf(sq * (1.f / 512.f) + 1e-5f);
    const float* gp = gg + lane * 8;
    const float* bp2 = bb + lane * 8;
    float4 g0 = *(const float4*)gp, g1 = *(const float4*)(gp + 4);
    float4 b0 = *(const float4*)bp2, b1 = *(const float4*)(bp2 + 4);
    float ga[8] = {g0.x,g0.y,g0.z,g0.w,g1.x,g1.y,g1.z,g1.w};
    float ba[8] = {b0.x,b0.y,b0.z,b0.w,b1.x,b1.y,b1.z,b1.w};
    float o[8];
#pragma unroll
    for (int i = 0; i < 8; ++i) o[i] = (v[i] - mu) * rstd * ga[i] + ba[i];
    float* ofp = outF + base;
    float4 w0; w0.x=o[0]; w0.y=o[1]; w0.z=o[2]; w0.w=o[3];
    float4 w1; w1.x=o[4]; w1.y=o[5]; w1.z=o[6]; w1.w=o[7];
    *(float4*)ofp = w0; *(float4*)(ofp + 4) = w1;
    unsigned short* obp = outB + base;
    ushort4 u0, u1;
    u0.x=f2bf(o[0]); u0.y=f2bf(o[1]); u0.z=f2bf(o[2]); u0.w=f2bf(o[3]);
    u1.x=f2bf(o[4]); u1.y=f2bf(o[5]); u1.z=f2bf(o[6]); u1.w=f2bf(o[7]);
    ((ushort4*)obp)[0] = u0; ((ushort4*)obp)[1] = u1;
}

// --- K8: plain LayerNorm w/ residual (128 rows) -----------------------------
__global__ __launch_bounds__(256) void k_ln(
    const float* __restrict__ X, const float* __restrict__ R,
    const float* __restrict__ gg, const float* __restrict__ bb,
    float* __restrict__ outF, unsigned short* __restrict__ outB, int rows)
{
    int wave = threadIdx.x >> 6, lane = threadIdx.x & 63;
    int row = blockIdx.x * 4 + wave;
    if (row >= rows) return;
    size_t base = (size_t)row * 512 + lane * 8;
    const float* xp = X + base;
    float v[8];
    { float4 a = *(const float4*)xp, b = *(const float4*)(xp + 4);
      v[0]=a.x; v[1]=a.y; v[2]=a.z; v[3]=a.w; v[4]=b.x; v[5]=b.y; v[6]=b.z; v[7]=b.w; }
    { const float* rp = R + base;
      float4 a = *(const float4*)rp, b = *(const float4*)(rp + 4);
      v[0]+=a.x; v[1]+=a.y; v[2]+=a.z; v[3]+=a.w; v[4]+=b.x; v[5]+=b.y; v[6]+=b.z; v[7]+=b.w; }
    float s = 0.f;
#pragma unroll
    for (int i = 0; i < 8; ++i) s += v[i];
#pragma unroll
    for (int m = 32; m; m >>= 1) s += __shfl_xor(s, m, 64);
    float mu = s * (1.f / 512.f);
    float sq = 0.f;
#pragma unroll
    for (int i = 0; i < 8; ++i) { float d = v[i] - mu; sq += d * d; }
#pragma unroll
    for (int m = 32; m; m >>= 1) sq += __shfl_xor(sq, m, 64);
    float rstd = rsqrtf(sq * (1.f / 512.f) + 1e-5f);
    const float* gp = gg + lane * 8;
    const float* bp = bb + lane * 8;
    float4 g0 = *(const float4*)gp, g1 = *(const float4*)(gp + 4);
    float4 b0 = *(const float4*)bp, b1 = *(const float4*)(bp + 4);
    float ga[8] = {g0.x,g0.y,g0.z,g0.w,g1.x,g1.y,g1.z,g1.w};
    float ba[8] = {b0.x,b0.y,b0.z,b0.w,b1.x,b1.y,b1.z,b1.w};
    float o[8];
#pragma unroll
    for (int i = 0; i < 8; ++i) o[i] = (v[i] - mu) * rstd * ga[i] + ba[i];
    float* ofp = outF + base;
    float4 w0; w0.x=o[0]; w0.y=o[1]; w0.z=o[2]; w0.w=o[3];
    float4 w1; w1.x=o[4]; w1.y=o[5]; w1.z=o[6]; w1.w=o[7];
    *(float4*)ofp = w0; *(float4*)(ofp + 4) = w1;
    unsigned short* obp = outB + base;
    ushort4 u0, u1;
    u0.x=f2bf(o[0]); u0.y=f2bf(o[1]); u0.z=f2bf(o[2]); u0.w=f2bf(o[3]);
    u1.x=f2bf(o[4]); u1.y=f2bf(o[5]); u1.z=f2bf(o[6]); u1.w=f2bf(o[7]);
    ((ushort4*)obp)[0] = u0; ((ushort4*)obp)[1] = u1;
}

// --- K9: attention per (b,h); QKV fp32 [1928 x 1536]; V staged in LDS bf16 --
__global__ __launch_bounds__(256) void k_attn(
    const float* __restrict__ QKV, unsigned short* __restrict__ attn_bf)
{
    int b = blockIdx.x, h = blockIdx.y;
    __shared__ __align__(16) float qs[16 * 64];
    __shared__ unsigned short Vs[225 * 64];
    __shared__ float sc[16 * 225];
    int t = threadIdx.x;
    for (int i = t; i < 1024; i += 256) {
        int p = i >> 6, d = i & 63;
        qs[i] = QKV[(size_t)(b * 16 + p) * 1536 + h * 64 + d];
    }
    for (int i = t; i < 14400; i += 256) {
        int l = i >> 6, d = i & 63;
        Vs[i] = f2bf(QKV[(size_t)(128 + b * 225 + l) * 1536 + 1024 + h * 64 + d]);
    }
    __syncthreads();
    for (int i = t; i < 3600; i += 256) {
        int p = i / 225, l = i - p * 225;
        const float4* k4 = (const float4*)(QKV + (size_t)(128 + b * 225 + l) * 1536 + 512 + h * 64);
        const float4* q4 = (const float4*)&qs[p * 64];
        float s = 0.f;
#pragma unroll
        for (int d = 0; d < 16; ++d) {
            float4 kk = k4[d], qq = q4[d];
            s += kk.x * qq.x + kk.y * qq.y + kk.z * qq.z + kk.w * qq.w;
        }
        sc[p * 225 + l] = s * 0.125f;   // 1/sqrt(64)
    }
    __syncthreads();
    int lane = t & 63, wave = t >> 6;
    int p = wave * 4 + (lane >> 4), sub = lane & 15;
    float m = -1e30f;
    for (int l = sub; l < 225; l += 16) m = fmaxf(m, sc[p * 225 + l]);
#pragma unroll
    for (int off = 8; off; off >>= 1) m = fmaxf(m, __shfl_xor(m, off, 16));
    float s = 0.f;
    for (int l = sub; l < 225; l += 16) {
        float e = __expf(sc[p * 225 + l] - m);
        sc[p * 225 + l] = e; s += e;
    }
#pragma unroll
    for (int off = 8; off; off >>= 1) s += __shfl_xor(s, off, 16);
    float inv = 1.f / s;
    for (int l = sub; l < 225; l += 16) sc[p * 225 + l] *= inv;
    __syncthreads();
    for (int i = t; i < 1024; i += 256) {
        int p2 = i >> 6, d = i & 63;
        float o = 0.f;
        for (int l = 0; l < 225; ++l) o += sc[p2 * 225 + l] * bf2f(Vs[l * 64 + d]);
        attn_bf[(size_t)(b * 16 + p2) * 512 + h * 64 + d] = f2bf(o);
    }
}

// --- K10: outs[128,2] = (gelu(M1)+res) @ Wc^T + bc, wave per row ------------
__global__ __launch_bounds__(256) void k_wc(
    const float* __restrict__ m1, const float* __restrict__ res,
    const float* __restrict__ Wc, const float* __restrict__ bc,
    float* __restrict__ outs)
{
    int wave = threadIdx.x >> 6, lane = threadIdx.x & 63;
    int row = blockIdx.x * 4 + wave;                     // 32 blocks x 4 waves
    size_t base = (size_t)row * 512 + lane * 8;
    const float* mp = m1 + base;
    const float* rp = res + base;
    const float* w0p = Wc + lane * 8;
    const float* w1p = Wc + 512 + lane * 8;
    float4 ma = *(const float4*)mp, mb = *(const float4*)(mp + 4);
    float4 ra = *(const float4*)rp, rb = *(const float4*)(rp + 4);
    float4 wa0 = *(const float4*)w0p, wb0 = *(const float4*)(w0p + 4);
    float4 wa1 = *(const float4*)w1p, wb1 = *(const float4*)(w1p + 4);
    float mv[8] = {ma.x,ma.y,ma.z,ma.w,mb.x,mb.y,mb.z,mb.w};
    float rv[8] = {ra.x,ra.y,ra.z,ra.w,rb.x,rb.y,rb.z,rb.w};
    float w0[8] = {wa0.x,wa0.y,wa0.z,wa0.w,wb0.x,wb0.y,wb0.z,wb0.w};
    float w1[8] = {wa1.x,wa1.y,wa1.z,wa1.w,wb1.x,wb1.y,wb1.z,wb1.w};
    float s0 = 0.f, s1 = 0.f;
#pragma unroll
    for (int i = 0; i < 8; ++i) {
        float v = mv[i];
        float x = 0.5f * v * (1.f + erff(v * 0.70710678118654752f)) + rv[i];
        s0 += x * w0[i]; s1 += x * w1[i];
    }
#pragma unroll
    for (int m = 32; m; m >>= 1) {
        s0 += __shfl_xor(s0, m, 64);
        s1 += __shfl_xor(s1, m, 64);
    }
    if (lane == 0) {
        outs[row * 2 + 0] = s0 + bc[0];
        outs[row * 2 + 1] = s1 + bc[1];
    }
}

// --- K11: zero helper --------------------------------------------------------
__global__ void k_zero(float* __restrict__ p, int n) {
    int t = blockIdx.x * blockDim.x + threadIdx.x;
    if (t < n) p[t] = 0.f;
}

// --- K12: segment histogram --------------------------------------------------
__global__ __launch_bounds__(256) void k_hist(
    const int* __restrict__ masks, const float* __restrict__ probs,
    float* __restrict__ sums, float* __restrict__ cnt)
{
    __shared__ float ls[68];
    int t = threadIdx.x;
    if (t < 68) ls[t] = 0.f;
    __syncthreads();
    int b = blockIdx.x >> 6, chunk = blockIdx.x & 63;
    int base = chunk * 1024;
    for (int it = 0; it < 4; ++it) {
        int px = base + it * 256 + t;
        int lab = masks[b * 65536 + px];
        atomicAdd(&ls[lab * 3 + 0], probs[(size_t)(b * 3 + 0) * 65536 + px]);
        atomicAdd(&ls[lab * 3 + 1], probs[(size_t)(b * 3 + 1) * 65536 + px]);
        atomicAdd(&ls[lab * 3 + 2], probs[(size_t)(b * 3 + 2) * 65536 + px]);
        atomicAdd(&ls[51 + lab], 1.f);
    }
    __syncthreads();
    if (t < 51)       atomicAdd(&sums[b * 51 + t], ls[t]);
    else if (t < 68)  atomicAdd(&cnt[b * 17 + t - 51], ls[t]);
}

// --- K13: newv table (8 x 17 x 3) --------------------------------------------
__global__ void k_newv(
    const float* __restrict__ seg, const float* __restrict__ outs,
    float* __restrict__ newv)
{
    int t = threadIdx.x;
    if (t >= 136) return;
    int lab = t % 17;
    const float* sums = seg;
    const float* cnt  = seg + 408;
    if (lab == 0) { newv[t*3+0] = 0.f; newv[t*3+1] = 0.f; newv[t*3+2] = 0.f; return; }
    int b = t / 17;
    float c  = fmaxf(cnt[t], 1.f);
    float m0 = sums[t*3+0] / c + 1e-6f;
    float m1 = sums[t*3+1] / c + 1e-6f;
    float m2 = sums[t*3+2] / c + 1e-6f;
    int p = lab - 1;
    float o0 = outs[(b*16+p)*2+0], o1 = outs[(b*16+p)*2+1];
    float new0 = m0 / (0.5f * (m1 + m2)) * (0.5f * (o0 + o1));
    newv[t*3+0] = new0; newv[t*3+1] = o0; newv[t*3+2] = o1;
}

// --- K14: final per-pixel gather ---------------------------------------------
__global__ __launch_bounds__(256) void k_out(
    const int* __restrict__ masks, const float* __restrict__ probs,
    const float* __restrict__ newv, float* __restrict__ out)
{
    int t = blockIdx.x * 256 + threadIdx.x;
    int b = t >> 16, hw = t & 65535;
    int lab = masks[t];
    if (lab > 0) {
        const float* nv = newv + (size_t)(b * 17 + lab) * 3;
        out[(size_t)(b*3+0)*65536 + hw] = nv[0];
        out[(size_t)(b*3+1)*65536 + hw] = nv[1];
        out[(size_t)(b*3+2)*65536 + hw] = nv[2];
    } else {
        out[(size_t)(b*3+0)*65536 + hw] = probs[(size_t)(b*3+0)*65536 + hw];
        out[(size_t)(b*3+1)*65536 + hw] = probs[(size_t)(b*3+1)*65536 + hw];
        out[(size_t)(b*3+2)*65536 + hw] = probs[(size_t)(b*3+2)*65536 + hw];
    }
}

// ---------------------------------------------------------------------------
extern "C" void kernel_launch(void* const* d_in, const int* in_sizes, int n_in,
                              void* d_out, int out_size, void* d_ws, size_t ws_size,
                              hipStream_t stream)
{
    const float* features = (const float*)d_in[0];
    const float* probs    = (const float*)d_in[1];
    const float* patches  = (const float*)d_in[2];
    const int*   masks    = (const int*)d_in[3];
    const float* ln_g     = (const float*)d_in[4];
    const float* ln_b     = (const float*)d_in[5];
    const float* Wr       = (const float*)d_in[6];
    const float* br       = (const float*)d_in[7];
    const float* Wqkv     = (const float*)d_in[8];
    const float* bqkv     = (const float*)d_in[9];
    const float* Wo       = (const float*)d_in[10];
    const float* bo       = (const float*)d_in[11];
    const float* Wm       = (const float*)d_in[12];
    const float* bm       = (const float*)d_in[13];
    const float* Wc       = (const float*)d_in[14];
    const float* bc       = (const float*)d_in[15];
    float* out = (float*)d_out;

    char* w = (char*)d_ws;
    size_t off = 0;
    auto alloc = [&](size_t bytes) -> char* {
        char* p = w + off;
        off += (bytes + 255) & ~(size_t)255;
        return p;
    };
    unsigned short* Gp     = (unsigned short*)alloc((size_t)2097152 * 2);
    unsigned short* Xb     = (unsigned short*)alloc((size_t)1928 * 4096 * 2);
    unsigned short* Wr_b   = (unsigned short*)alloc((size_t)2097152 * 2);
    unsigned short* Wqkv_b = (unsigned short*)alloc((size_t)786432 * 2);
    unsigned short* Wo_b   = (unsigned short*)alloc((size_t)262144 * 2);
    unsigned short* Wm_b   = (unsigned short*)alloc((size_t)262144 * 2);
    float* Yp   = (float*)alloc((size_t)4 * 1928 * 512 * 4);   // split-K partials
    float* LNf  = (float*)alloc((size_t)1928 * 512 * 4);
    unsigned short* LNb = (unsigned short*)alloc((size_t)1928 * 512 * 2);
    float* QKV  = (float*)alloc((size_t)1928 * 1536 * 4);
    unsigned short* attnb = (unsigned short*)alloc((size_t)65536 * 2);
    float* Zo   = (float*)alloc((size_t)65536 * 4);
    float* resf = (float*)alloc((size_t)65536 * 4);
    unsigned short* resb = (unsigned short*)alloc((size_t)65536 * 2);
    float* M1   = (float*)alloc((size_t)65536 * 4);
    float* outsB = (float*)alloc((size_t)256 * 4);
    float* seg   = (float*)alloc((size_t)544 * 4);
    float* newv  = (float*)alloc((size_t)408 * 4);

    k_zero<<<3, 256, 0, stream>>>(seg, 544);

    k_pool_features<<<8192, 256, 0, stream>>>(features, Gp);
    k_pool_patches<<<2048, 256, 0, stream>>>(patches, Xb);
    k_gather_blocks<<<3600, 256, 0, stream>>>(Gp, Xb);
    k_f2bf_all<<<3328, 256, 0, stream>>>(Wr, Wqkv, Wo, Wm, Wr_b, Wqkv_b, Wo_b, Wm_b);

    // GEMM1 split-K=4: Yp[s] = X @ Wr^T (1928 x 4096/4 x 512), 256 blocks
    k_gemm128<<<dim3(4, 16, 4), 256, 0, stream>>>(Xb, Wr_b, nullptr, Yp, 1928, 512, 4096, 1024);
    k_lnred<<<482, 256, 0, stream>>>(Yp, br, ln_g, ln_b, LNf, LNb, 1928);

    // fused QKV: [1928 x 1536] = LNb @ Wqkv^T + bqkv (192 blocks)
    k_gemm128<<<dim3(12, 16, 1), 256, 0, stream>>>(LNb, Wqkv_b, bqkv, QKV, 1928, 1536, 512, 512);

    k_attn<<<dim3(8, 8), 256, 0, stream>>>(QKV, attnb);

    k_gemm_nt<<<dim3(8, 2), 256, 0, stream>>>(attnb, Wo_b, bo, Zo, 128, 512, 512);
    k_ln<<<32, 256, 0, stream>>>(Zo, LNf, ln_g, ln_b, resf, resb, 128);

    k_gemm_nt<<<dim3(8, 2), 256, 0, stream>>>(resb, Wm_b, bm, M1, 128, 512, 512);
    k_wc<<<32, 256, 0, stream>>>(M1, resf, Wc, bc, outsB);

    k_hist<<<512, 256, 0, stream>>>(masks, probs, seg, seg + 408);
    k_newv<<<1, 256, 0, stream>>>(seg, outsB, newv);
    k_out<<<2048, 256, 0, stream>>>(masks, probs, newv, out);
}

// Round 4
// 367.993 us; speedup vs baseline: 1.5291x; 1.1048x over previous
//
#include <hip/hip_runtime.h>
#include <stdint.h>

// ---------------------------------------------------------------------------
// WeedLayer. B=8, C=64, H=W=256, PD=32, STRIDE=16 -> n=15, L=225, P=16, E=512,
// HEADS=8, hd=64, fv=4096. X = [patches(128); blocks(1800)] = 1928 rows.
// R4: k_attn 256 blocks + LDS bf16 K/V (padded); QKV split-K=2 reduced in
//     attn; GEMM1 split-K=8 (2 blocks/CU); k_prep mega-fusion; per-wave hist;
//     newv folded into k_out. 12 dispatches total.
// ---------------------------------------------------------------------------

typedef __attribute__((ext_vector_type(8))) short bf16x8;
typedef __attribute__((ext_vector_type(4))) float f32x4;

__device__ __forceinline__ unsigned short f2bf(float x) {
    union { float f; unsigned u; } v; v.f = x;
    unsigned r = v.u + 0x7FFFu + ((v.u >> 16) & 1u);   // RNE
    return (unsigned short)(r >> 16);
}
__device__ __forceinline__ float bf2f(unsigned short x) {
    union { unsigned u; float f; } v; v.u = ((unsigned)x) << 16; return v.f;
}

__device__ __forceinline__ void g2l16(const unsigned short* g, unsigned short* l) {
    __builtin_amdgcn_global_load_lds(
        (const __attribute__((address_space(1))) unsigned int*)g,
        (__attribute__((address_space(3))) unsigned int*)l, 16, 0, 0);
}

// --- K_prep: pool_features | pool_patches | weight f2bf | seg zero ----------
__global__ __launch_bounds__(256) void k_prep(
    const float* __restrict__ f, const float* __restrict__ p,
    const float* __restrict__ Wr, const float* __restrict__ Wqkv,
    const float* __restrict__ Wo, const float* __restrict__ Wm,
    unsigned short* __restrict__ gp, unsigned short* __restrict__ Xb,
    unsigned short* __restrict__ oWr, unsigned short* __restrict__ oWqkv,
    unsigned short* __restrict__ oWo, unsigned short* __restrict__ oWm,
    float* __restrict__ seg)
{
    int blk = blockIdx.x, tid = threadIdx.x;
    if (blk < 8192) {
        if (blk == 0) for (int i = tid; i < 544; i += 256) seg[i] = 0.f;
        unsigned t = blk * 256u + tid;                   // 2,097,152
        unsigned q = t & 127u, r = (t >> 7) & 127u, g = (t >> 14) & 15u, b = t >> 18;
        const float2* f2 = (const float2*)f;
        float s = 0.f;
        unsigned cb = b * 64u + g * 4u;
#pragma unroll
        for (int j = 0; j < 4; ++j)
#pragma unroll
            for (int a = 0; a < 2; ++a) {
                unsigned idx = ((cb + j) * 256u + 2u * r + a) * 256u + 2u * q;
                float2 v = f2[idx >> 1];
                s += v.x + v.y;
            }
        gp[t] = f2bf(s * 0.0625f);
    } else if (blk < 10240) {
        unsigned t = (blk - 8192) * 256u + tid;          // 524,288
        unsigned i = t & 4095u, row = t >> 12;
        unsigned q = i & 15u, r = (i >> 4) & 15u, g = i >> 8;
        const float2* p2 = (const float2*)p;
        float s = 0.f;
        unsigned cb = row * 64u + g * 4u;
#pragma unroll
        for (int j = 0; j < 4; ++j)
#pragma unroll
            for (int a = 0; a < 2; ++a) {
                unsigned idx = ((cb + j) * 32u + 2u * r + a) * 32u + 2u * q;
                float2 v = p2[idx >> 1];
                s += v.x + v.y;
            }
        Xb[(size_t)row * 4096 + i] = f2bf(s * 0.0625f);
    } else {
        int t = (blk - 10240) * 256 + tid;               // 851,968 float4 groups
        const float* src; unsigned short* dst; int i;
        if (t < 524288)      { src = Wr;   dst = oWr;   i = t; }
        else if (t < 720896) { src = Wqkv; dst = oWqkv; i = t - 524288; }
        else if (t < 786432) { src = Wo;   dst = oWo;   i = t - 720896; }
        else                 { src = Wm;   dst = oWm;   i = t - 786432; }
        float4 v = ((const float4*)src)[i];
        ushort4 o;
        o.x = f2bf(v.x); o.y = f2bf(v.y); o.z = f2bf(v.z); o.w = f2bf(v.w);
        ((ushort4*)dst)[i] = o;
    }
}

// --- gather block crops from Gp -> X rows 128..1927 -------------------------
__global__ __launch_bounds__(256) void k_gather_blocks(
    const unsigned short* __restrict__ Gp, unsigned short* __restrict__ Xb)
{
    unsigned t = blockIdx.x * 256u + threadIdx.x;
    unsigned grp = t & 511u, row_rel = t >> 9;
    unsigned k0 = grp * 8u;
    unsigned g = k0 >> 8, r = (k0 >> 4) & 15u, q0 = k0 & 15u;
    unsigned b = row_rel / 225u;
    unsigned ij = row_rel - b * 225u;
    unsigned i = ij / 15u, j = ij - i * 15u;
    size_t src = ((size_t)(b * 16u + g) * 128u + i * 8u + r) * 128u + j * 8u + q0;
    size_t dst = (size_t)(128u + row_rel) * 4096u + k0;
    *(uint4*)(Xb + dst) = *(const uint4*)(Gp + src);
}

// --- 128x128-tile bf16 NT GEMM (m97 structure), split-K ---------------------
__global__ __launch_bounds__(256) void k_gemm128(
    const unsigned short* __restrict__ A, const unsigned short* __restrict__ Bw,
    const float* __restrict__ bias, float* __restrict__ C,
    int M, int N, int K, int klen)
{
    __shared__ __align__(16) unsigned short As[128 * 32];
    __shared__ __align__(16) unsigned short Bs[128 * 32];
    const int tid = threadIdx.x, w = tid >> 6, lane = tid & 63;
    const int nt = blockIdx.x, mt = blockIdx.y, ks = blockIdx.z;
    const int kbase = ks * klen;
    const int l15 = lane & 15, kq = (lane >> 4) * 8;
    const int wm = (w >> 1) * 64, wn = (w & 1) * 64;
    const int srow0 = w * 32, lrow = lane >> 2, lcol = (lane & 3) * 8;

    f32x4 acc[4][4];
#pragma unroll
    for (int i = 0; i < 4; ++i)
#pragma unroll
        for (int j = 0; j < 4; ++j) acc[i][j] = (f32x4){0.f, 0.f, 0.f, 0.f};

    int arow0 = mt * 128, brow0 = nt * 128;
    for (int k0 = 0; k0 < klen; k0 += 32) {
        int kk = kbase + k0;
#pragma unroll
        for (int c = 0; c < 2; ++c) {
            int r = srow0 + c * 16 + lrow;
            int ga = arow0 + r; if (ga > M - 1) ga = M - 1;
            g2l16(A + (size_t)ga * K + kk + lcol, &As[(srow0 + c * 16) * 32]);
            g2l16(Bw + (size_t)(brow0 + r) * K + kk + lcol, &Bs[(srow0 + c * 16) * 32]);
        }
        __syncthreads();
        bf16x8 af[4], bf[4];
#pragma unroll
        for (int i = 0; i < 4; ++i) {
            af[i] = *(const bf16x8*)&As[(wm + 16 * i + l15) * 32 + kq];
            bf[i] = *(const bf16x8*)&Bs[(wn + 16 * i + l15) * 32 + kq];
        }
#pragma unroll
        for (int i = 0; i < 4; ++i)
#pragma unroll
            for (int j = 0; j < 4; ++j)
                acc[i][j] = __builtin_amdgcn_mfma_f32_16x16x32_bf16(af[i], bf[j], acc[i][j], 0, 0, 0);
        __syncthreads();
    }
    float* Cp = C + (size_t)ks * M * N;
#pragma unroll
    for (int i = 0; i < 4; ++i) {
        int rowb = mt * 128 + wm + i * 16 + (lane >> 4) * 4;
#pragma unroll
        for (int j = 0; j < 4; ++j) {
            int col = nt * 128 + wn + j * 16 + l15;
            float bv = bias ? bias[col] : 0.f;
#pragma unroll
            for (int r = 0; r < 4; ++r) {
                int row = rowb + r;
                if (row < M) Cp[(size_t)row * N + col] = acc[i][j][r] + bv;
            }
        }
    }
}

// --- small 64x64 NT GEMM for the 128-row layers -----------------------------
__global__ __launch_bounds__(256) void k_gemm_nt(
    const unsigned short* __restrict__ A, const unsigned short* __restrict__ Bw,
    const float* __restrict__ bias, float* __restrict__ C,
    int M, int N, int K)
{
    __shared__ __align__(16) unsigned short As[64 * 32];
    __shared__ __align__(16) unsigned short Bs[64 * 32];
    const int tid = threadIdx.x;
    const int bm = blockIdx.y, bn = blockIdx.x;
    const int wave = tid >> 6, lane = tid & 63;
    const int wm = (wave >> 1) * 32, wn = (wave & 1) * 32;
    const int l15 = lane & 15, kq = (lane >> 4) * 8;
    const int srow = tid >> 2, scol = (tid & 3) * 8;
    const unsigned short* Ap = A + (size_t)(bm * 64 + srow) * K + scol;
    const unsigned short* Bp = Bw + (size_t)(bn * 64 + srow) * K + scol;

    f32x4 acc[2][2];
#pragma unroll
    for (int i = 0; i < 2; ++i)
#pragma unroll
        for (int j = 0; j < 2; ++j) acc[i][j] = (f32x4){0.f, 0.f, 0.f, 0.f};

    for (int k0 = 0; k0 < K; k0 += 32) {
        *(uint4*)&As[srow * 32 + scol] = *(const uint4*)(Ap + k0);
        *(uint4*)&Bs[srow * 32 + scol] = *(const uint4*)(Bp + k0);
        __syncthreads();
        bf16x8 a0 = *(const bf16x8*)&As[(wm + l15) * 32 + kq];
        bf16x8 a1 = *(const bf16x8*)&As[(wm + 16 + l15) * 32 + kq];
        bf16x8 b0 = *(const bf16x8*)&Bs[(wn + l15) * 32 + kq];
        bf16x8 b1 = *(const bf16x8*)&Bs[(wn + 16 + l15) * 32 + kq];
        acc[0][0] = __builtin_amdgcn_mfma_f32_16x16x32_bf16(a0, b0, acc[0][0], 0, 0, 0);
        acc[0][1] = __builtin_amdgcn_mfma_f32_16x16x32_bf16(a0, b1, acc[0][1], 0, 0, 0);
        acc[1][0] = __builtin_amdgcn_mfma_f32_16x16x32_bf16(a1, b0, acc[1][0], 0, 0, 0);
        acc[1][1] = __builtin_amdgcn_mfma_f32_16x16x32_bf16(a1, b1, acc[1][1], 0, 0, 0);
        __syncthreads();
    }
#pragma unroll
    for (int it = 0; it < 2; ++it) {
        int rowb = bm * 64 + wm + it * 16 + (lane >> 4) * 4;
#pragma unroll
        for (int iu = 0; iu < 2; ++iu) {
            int col = bn * 64 + wn + iu * 16 + l15;
            float bv = bias[col];
#pragma unroll
            for (int r = 0; r < 4; ++r) {
                int row = rowb + r;
                if (row < M) C[(size_t)row * N + col] = acc[it][iu][r] + bv;
            }
        }
    }
}

// --- nsplit-partial reduce + bias + LayerNorm (wave/row) --------------------
__global__ __launch_bounds__(256) void k_lnred(
    const float* __restrict__ Yp, const float* __restrict__ br,
    const float* __restrict__ gg, const float* __restrict__ bb,
    float* __restrict__ outF, unsigned short* __restrict__ outB,
    int rows, int nsplit)
{
    int wave = threadIdx.x >> 6, lane = threadIdx.x & 63;
    int row = blockIdx.x * 4 + wave;
    if (row >= rows) return;
    size_t base = (size_t)row * 512 + lane * 8;
    float v[8];
    { const float* bp = br + lane * 8;
      float4 a = *(const float4*)bp, b = *(const float4*)(bp + 4);
      v[0]=a.x; v[1]=a.y; v[2]=a.z; v[3]=a.w; v[4]=b.x; v[5]=b.y; v[6]=b.z; v[7]=b.w; }
    for (int s = 0; s < nsplit; ++s) {
        const float* xp = Yp + (size_t)s * rows * 512 + base;
        float4 a = *(const float4*)xp, b = *(const float4*)(xp + 4);
        v[0]+=a.x; v[1]+=a.y; v[2]+=a.z; v[3]+=a.w; v[4]+=b.x; v[5]+=b.y; v[6]+=b.z; v[7]+=b.w;
    }
    float s = 0.f;
#pragma unroll
    for (int i = 0; i < 8; ++i) s += v[i];
#pragma unroll
    for (int m = 32; m; m >>= 1) s += __shfl_xor(s, m, 64);
    float mu = s * (1.f / 512.f);
    float sq = 0.f;
#pragma unroll
    for (int i = 0; i < 8; ++i) { float d = v[i] - mu; sq += d * d; }
#pragma unroll
    for (int m = 32; m; m >>= 1) sq += __shfl_xor(sq, m, 64);
    float rstd = rsqrtf(sq * (1.f / 512.f) + 1e-5f);
    const float* gp = gg + lane * 8;
    const float* bp2 = bb + lane * 8;
    float4 g0 = *(const float4*)gp, g1 = *(const float4*)(gp + 4);
    float4 b0 = *(const float4*)bp2, b1 = *(const float4*)(bp2 + 4);
    float ga[8] = {g0.x,g0.y,g0.z,g0.w,g1.x,g1.y,g1.z,g1.w};
    float ba[8] = {b0.x,b0.y,b0.z,b0.w,b1.x,b1.y,b1.z,b1.w};
    float o[8];
#pragma unroll
    for (int i = 0; i < 8; ++i) o[i] = (v[i] - mu) * rstd * ga[i] + ba[i];
    float* ofp = outF + base;
    float4 w0; w0.x=o[0]; w0.y=o[1]; w0.z=o[2]; w0.w=o[3];
    float4 w1; w1.x=o[4]; w1.y=o[5]; w1.z=o[6]; w1.w=o[7];
    *(float4*)ofp = w0; *(float4*)(ofp + 4) = w1;
    unsigned short* obp = outB + base;
    ushort4 u0, u1;
    u0.x=f2bf(o[0]); u0.y=f2bf(o[1]); u0.z=f2bf(o[2]); u0.w=f2bf(o[3]);
    u1.x=f2bf(o[4]); u1.y=f2bf(o[5]); u1.z=f2bf(o[6]); u1.w=f2bf(o[7]);
    ((ushort4*)obp)[0] = u0; ((ushort4*)obp)[1] = u1;
}

// --- plain LayerNorm w/ residual (128 rows) ---------------------------------
__global__ __launch_bounds__(256) void k_ln(
    const float* __restrict__ X, const float* __restrict__ R,
    const float* __restrict__ gg, const float* __restrict__ bb,
    float* __restrict__ outF, unsigned short* __restrict__ outB, int rows)
{
    int wave = threadIdx.x >> 6, lane = threadIdx.x & 63;
    int row = blockIdx.x * 4 + wave;
    if (row >= rows) return;
    size_t base = (size_t)row * 512 + lane * 8;
    const float* xp = X + base;
    float v[8];
    { float4 a = *(const float4*)xp, b = *(const float4*)(xp + 4);
      v[0]=a.x; v[1]=a.y; v[2]=a.z; v[3]=a.w; v[4]=b.x; v[5]=b.y; v[6]=b.z; v[7]=b.w; }
    { const float* rp = R + base;
      float4 a = *(const float4*)rp, b = *(const float4*)(rp + 4);
      v[0]+=a.x; v[1]+=a.y; v[2]+=a.z; v[3]+=a.w; v[4]+=b.x; v[5]+=b.y; v[6]+=b.z; v[7]+=b.w; }
    float s = 0.f;
#pragma unroll
    for (int i = 0; i < 8; ++i) s += v[i];
#pragma unroll
    for (int m = 32; m; m >>= 1) s += __shfl_xor(s, m, 64);
    float mu = s * (1.f / 512.f);
    float sq = 0.f;
#pragma unroll
    for (int i = 0; i < 8; ++i) { float d = v[i] - mu; sq += d * d; }
#pragma unroll
    for (int m = 32; m; m >>= 1) sq += __shfl_xor(sq, m, 64);
    float rstd = rsqrtf(sq * (1.f / 512.f) + 1e-5f);
    const float* gp = gg + lane * 8;
    const float* bp = bb + lane * 8;
    float4 g0 = *(const float4*)gp, g1 = *(const float4*)(gp + 4);
    float4 b0 = *(const float4*)bp, b1 = *(const float4*)(bp + 4);
    float ga[8] = {g0.x,g0.y,g0.z,g0.w,g1.x,g1.y,g1.z,g1.w};
    float ba[8] = {b0.x,b0.y,b0.z,b0.w,b1.x,b1.y,b1.z,b1.w};
    float o[8];
#pragma unroll
    for (int i = 0; i < 8; ++i) o[i] = (v[i] - mu) * rstd * ga[i] + ba[i];
    float* ofp = outF + base;
    float4 w0; w0.x=o[0]; w0.y=o[1]; w0.z=o[2]; w0.w=o[3];
    float4 w1; w1.x=o[4]; w1.y=o[5]; w1.z=o[6]; w1.w=o[7];
    *(float4*)ofp = w0; *(float4*)(ofp + 4) = w1;
    unsigned short* obp = outB + base;
    ushort4 u0, u1;
    u0.x=f2bf(o[0]); u0.y=f2bf(o[1]); u0.z=f2bf(o[2]); u0.w=f2bf(o[3]);
    u1.x=f2bf(o[4]); u1.y=f2bf(o[5]); u1.z=f2bf(o[6]); u1.w=f2bf(o[7]);
    ((ushort4*)obp)[0] = u0; ((ushort4*)obp)[1] = u1;
}

// --- attention: grid (8b, 8h, 4pz), 4 queries/block; QKV = 2 split partials -
__global__ __launch_bounds__(256) void k_attn(
    const float* __restrict__ QKVp, const float* __restrict__ bqkv,
    unsigned short* __restrict__ attn_bf)
{
    const int b = blockIdx.x, h = blockIdx.y, pz = blockIdx.z;
    const size_t PS = (size_t)1928 * 1536;
    __shared__ __align__(16) float qs[4 * 64];
    __shared__ __align__(16) unsigned short Ks[225 * 68];  // padded: stride 68
    __shared__ __align__(16) unsigned short Vs[225 * 64];
    __shared__ float sc[4 * 225];
    const int t = threadIdx.x;

    {   // stage Q (4 rows x 64)
        int p = t >> 6, d = t & 63;
        size_t idx = (size_t)(b * 16 + pz * 4 + p) * 1536 + h * 64 + d;
        qs[t] = QKVp[idx] + QKVp[PS + idx] + bqkv[h * 64 + d];
    }
    float bk = bqkv[512 + h * 64 + (t & 63)];
    float bv = bqkv[1024 + h * 64 + (t & 63)];
    for (int i = t; i < 14400; i += 256) {
        int l = i >> 6, d = i & 63;
        size_t base = (size_t)(128 + b * 225 + l) * 1536 + h * 64 + d;
        Ks[l * 68 + d] = f2bf(QKVp[base + 512] + QKVp[PS + base + 512] + bk);
        Vs[l * 64 + d] = f2bf(QKVp[base + 1024] + QKVp[PS + base + 1024] + bv);
    }
    __syncthreads();
    // scores: 900 items = 4 p x 225 l
    for (int i = t; i < 900; i += 256) {
        int p = i / 225, l = i - p * 225;
        const ushort4* k4 = (const ushort4*)&Ks[l * 68];
        const float4* q4 = (const float4*)&qs[p * 64];
        float s = 0.f;
#pragma unroll
        for (int d = 0; d < 16; ++d) {
            ushort4 kk = k4[d]; float4 qq = q4[d];
            s += bf2f(kk.x) * qq.x + bf2f(kk.y) * qq.y
               + bf2f(kk.z) * qq.z + bf2f(kk.w) * qq.w;
        }
        sc[p * 225 + l] = s * 0.125f;   // 1/sqrt(64)
    }
    __syncthreads();
    // softmax: wave per row
    const int lane = t & 63, wave = t >> 6;
    {
        float* row = &sc[wave * 225];
        float m = -1e30f;
        for (int l = lane; l < 225; l += 64) m = fmaxf(m, row[l]);
#pragma unroll
        for (int off = 32; off; off >>= 1) m = fmaxf(m, __shfl_xor(m, off, 64));
        float s = 0.f;
        for (int l = lane; l < 225; l += 64) { float e = __expf(row[l] - m); row[l] = e; s += e; }
#pragma unroll
        for (int off = 32; off; off >>= 1) s += __shfl_xor(s, off, 64);
        float inv = 1.f / s;
        for (int l = lane; l < 225; l += 64) row[l] *= inv;
    }
    __syncthreads();
    // PV: one output per thread (p=wave, d=lane)
    {
        float o = 0.f;
        const float* scp = &sc[wave * 225];
        for (int l = 0; l < 225; ++l) o += scp[l] * bf2f(Vs[l * 64 + lane]);
        attn_bf[(size_t)(b * 16 + pz * 4 + wave) * 512 + h * 64 + lane] = f2bf(o);
    }
}

// --- outs[128,2] = (gelu(M1)+res) @ Wc^T + bc, wave per row -----------------
__global__ __launch_bounds__(256) void k_wc(
    const float* __restrict__ m1, const float* __restrict__ res,
    const float* __restrict__ Wc, const float* __restrict__ bc,
    float* __restrict__ outs)
{
    int wave = threadIdx.x >> 6, lane = threadIdx.x & 63;
    int row = blockIdx.x * 4 + wave;
    size_t base = (size_t)row * 512 + lane * 8;
    const float* mp = m1 + base;
    const float* rp = res + base;
    const float* w0p = Wc + lane * 8;
    const float* w1p = Wc + 512 + lane * 8;
    float4 ma = *(const float4*)mp, mb = *(const float4*)(mp + 4);
    float4 ra = *(const float4*)rp, rb = *(const float4*)(rp + 4);
    float4 wa0 = *(const float4*)w0p, wb0 = *(const float4*)(w0p + 4);
    float4 wa1 = *(const float4*)w1p, wb1 = *(const float4*)(w1p + 4);
    float mv[8] = {ma.x,ma.y,ma.z,ma.w,mb.x,mb.y,mb.z,mb.w};
    float rv[8] = {ra.x,ra.y,ra.z,ra.w,rb.x,rb.y,rb.z,rb.w};
    float w0[8] = {wa0.x,wa0.y,wa0.z,wa0.w,wb0.x,wb0.y,wb0.z,wb0.w};
    float w1[8] = {wa1.x,wa1.y,wa1.z,wa1.w,wb1.x,wb1.y,wb1.z,wb1.w};
    float s0 = 0.f, s1 = 0.f;
#pragma unroll
    for (int i = 0; i < 8; ++i) {
        float v = mv[i];
        float x = 0.5f * v * (1.f + erff(v * 0.70710678118654752f)) + rv[i];
        s0 += x * w0[i]; s1 += x * w1[i];
    }
#pragma unroll
    for (int m = 32; m; m >>= 1) {
        s0 += __shfl_xor(s0, m, 64);
        s1 += __shfl_xor(s1, m, 64);
    }
    if (lane == 0) {
        outs[row * 2 + 0] = s0 + bc[0];
        outs[row * 2 + 1] = s1 + bc[1];
    }
}

// --- segment histogram, per-wave LDS accumulators ---------------------------
__global__ __launch_bounds__(256) void k_hist(
    const int* __restrict__ masks, const float* __restrict__ probs,
    float* __restrict__ sums, float* __restrict__ cnt)
{
    __shared__ float ls[4][68];
    int t = threadIdx.x, wave = t >> 6;
    for (int i = t; i < 272; i += 256) ((float*)ls)[i] = 0.f;
    __syncthreads();
    int b = blockIdx.x >> 6, chunk = blockIdx.x & 63;
    int base = chunk * 1024;
    for (int it = 0; it < 4; ++it) {
        int px = base + it * 256 + t;
        int lab = masks[b * 65536 + px];
        atomicAdd(&ls[wave][lab * 3 + 0], probs[(size_t)(b * 3 + 0) * 65536 + px]);
        atomicAdd(&ls[wave][lab * 3 + 1], probs[(size_t)(b * 3 + 1) * 65536 + px]);
        atomicAdd(&ls[wave][lab * 3 + 2], probs[(size_t)(b * 3 + 2) * 65536 + px]);
        atomicAdd(&ls[wave][51 + lab], 1.f);
    }
    __syncthreads();
    if (t < 68) {
        float v = ls[0][t] + ls[1][t] + ls[2][t] + ls[3][t];
        if (t < 51) atomicAdd(&sums[b * 51 + t], v);
        else        atomicAdd(&cnt[b * 17 + t - 51], v);
    }
}

// --- final gather, newv table computed per-block ----------------------------
__global__ __launch_bounds__(256) void k_out(
    const int* __restrict__ masks, const float* __restrict__ probs,
    const float* __restrict__ seg, const float* __restrict__ outs,
    float* __restrict__ out)
{
    __shared__ float nv[17 * 3];
    int tid = threadIdx.x;
    int b = blockIdx.x >> 8;
    if (tid < 17) {
        int lab = tid;
        if (lab == 0) { nv[0] = 0.f; nv[1] = 0.f; nv[2] = 0.f; }
        else {
            float c  = fmaxf(seg[408 + b * 17 + lab], 1.f);
            float m0 = seg[(b * 17 + lab) * 3 + 0] / c + 1e-6f;
            float m1 = seg[(b * 17 + lab) * 3 + 1] / c + 1e-6f;
            float m2 = seg[(b * 17 + lab) * 3 + 2] / c + 1e-6f;
            int p = lab - 1;
            float o0 = outs[(b * 16 + p) * 2 + 0], o1 = outs[(b * 16 + p) * 2 + 1];
            nv[lab * 3 + 0] = m0 / (0.5f * (m1 + m2)) * (0.5f * (o0 + o1));
            nv[lab * 3 + 1] = o0;
            nv[lab * 3 + 2] = o1;
        }
    }
    __syncthreads();
    int px = (blockIdx.x & 255) * 256 + tid;
    int gl = b * 65536 + px;
    int lab = masks[gl];
    if (lab > 0) {
        out[(size_t)(b*3+0)*65536 + px] = nv[lab*3+0];
        out[(size_t)(b*3+1)*65536 + px] = nv[lab*3+1];
        out[(size_t)(b*3+2)*65536 + px] = nv[lab*3+2];
    } else {
        out[(size_t)(b*3+0)*65536 + px] = probs[(size_t)(b*3+0)*65536 + px];
        out[(size_t)(b*3+1)*65536 + px] = probs[(size_t)(b*3+1)*65536 + px];
        out[(size_t)(b*3+2)*65536 + px] = probs[(size_t)(b*3+2)*65536 + px];
    }
}

// ---------------------------------------------------------------------------
extern "C" void kernel_launch(void* const* d_in, const int* in_sizes, int n_in,
                              void* d_out, int out_size, void* d_ws, size_t ws_size,
                              hipStream_t stream)
{
    const float* features = (const float*)d_in[0];
    const float* probs    = (const float*)d_in[1];
    const float* patches  = (const float*)d_in[2];
    const int*   masks    = (const int*)d_in[3];
    const float* ln_g     = (const float*)d_in[4];
    const float* ln_b     = (const float*)d_in[5];
    const float* Wr       = (const float*)d_in[6];
    const float* br       = (const float*)d_in[7];
    const float* Wqkv     = (const float*)d_in[8];
    const float* bqkv     = (const float*)d_in[9];
    const float* Wo       = (const float*)d_in[10];
    const float* bo       = (const float*)d_in[11];
    const float* Wm       = (const float*)d_in[12];
    const float* bm       = (const float*)d_in[13];
    const float* Wc       = (const float*)d_in[14];
    const float* bc       = (const float*)d_in[15];
    float* out = (float*)d_out;

    char* w = (char*)d_ws;
    size_t off = 0;
    auto alloc = [&](size_t bytes) -> char* {
        char* p = w + off;
        off += (bytes + 255) & ~(size_t)255;
        return p;
    };
    unsigned short* Gp     = (unsigned short*)alloc((size_t)2097152 * 2);
    unsigned short* Xb     = (unsigned short*)alloc((size_t)1928 * 4096 * 2);
    unsigned short* Wr_b   = (unsigned short*)alloc((size_t)2097152 * 2);
    unsigned short* Wqkv_b = (unsigned short*)alloc((size_t)786432 * 2);
    unsigned short* Wo_b   = (unsigned short*)alloc((size_t)262144 * 2);
    unsigned short* Wm_b   = (unsigned short*)alloc((size_t)262144 * 2);
    float* Yp   = (float*)alloc((size_t)8 * 1928 * 512 * 4);   // split-K=8 partials
    float* LNf  = (float*)alloc((size_t)1928 * 512 * 4);
    unsigned short* LNb = (unsigned short*)alloc((size_t)1928 * 512 * 2);
    float* QKV  = (float*)alloc((size_t)2 * 1928 * 1536 * 4);  // split-K=2 partials
    unsigned short* attnb = (unsigned short*)alloc((size_t)65536 * 2);
    float* Zo   = (float*)alloc((size_t)65536 * 4);
    float* resf = (float*)alloc((size_t)65536 * 4);
    unsigned short* resb = (unsigned short*)alloc((size_t)65536 * 2);
    float* M1   = (float*)alloc((size_t)65536 * 4);
    float* outsB = (float*)alloc((size_t)256 * 4);
    float* seg   = (float*)alloc((size_t)544 * 4);   // 408 sums + 136 cnt

    // 1: pools + weight cvt + seg zero
    k_prep<<<13568, 256, 0, stream>>>(features, patches, Wr, Wqkv, Wo, Wm,
                                      Gp, Xb, Wr_b, Wqkv_b, Wo_b, Wm_b, seg);
    // 2: block gather
    k_gather_blocks<<<3600, 256, 0, stream>>>(Gp, Xb);
    // 3: GEMM1 split-K=8 (512 blocks)
    k_gemm128<<<dim3(4, 16, 8), 256, 0, stream>>>(Xb, Wr_b, nullptr, Yp, 1928, 512, 4096, 512);
    // 4: reduce + br + LN1
    k_lnred<<<482, 256, 0, stream>>>(Yp, br, ln_g, ln_b, LNf, LNb, 1928, 8);
    // 5: QKV split-K=2 (384 blocks), bias/reduce folded into attn
    k_gemm128<<<dim3(12, 16, 2), 256, 0, stream>>>(LNb, Wqkv_b, nullptr, QKV, 1928, 1536, 512, 256);
    // 6: attention (256 blocks)
    k_attn<<<dim3(8, 8, 4), 256, 0, stream>>>(QKV, bqkv, attnb);
    // 7-8: Wo proj + residual LN
    k_gemm_nt<<<dim3(8, 2), 256, 0, stream>>>(attnb, Wo_b, bo, Zo, 128, 512, 512);
    k_ln<<<32, 256, 0, stream>>>(Zo, LNf, ln_g, ln_b, resf, resb, 128);
    // 9-10: MLP + classifier
    k_gemm_nt<<<dim3(8, 2), 256, 0, stream>>>(resb, Wm_b, bm, M1, 128, 512, 512);
    k_wc<<<32, 256, 0, stream>>>(M1, resf, Wc, bc, outsB);
    // 11: segment stats
    k_hist<<<512, 256, 0, stream>>>(masks, probs, seg, seg + 408);
    // 12: final gather (newv recomputed per block)
    k_out<<<2048, 256, 0, stream>>>(masks, probs, seg, outsB, out);
}